// Round 1
// baseline (650.200 us; speedup 1.0000x reference)
//
#include <hip/hip_runtime.h>

#define IN_DIM 1024
#define HID 32

__device__ __forceinline__ float selu_f(float x) {
    const float scale = 1.0507009873554805f;
    const float alpha = 1.6732632423543772f;
    return x > 0.f ? scale * x : scale * alpha * (expf(x) - 1.f);
}

// ---------------- CSR build ----------------

__global__ void zero_i32(int* __restrict__ p, int n) {
    int i = blockIdx.x * blockDim.x + threadIdx.x;
    if (i < n) p[i] = 0;
}

__global__ void hist_kernel(const int* __restrict__ rows, int E, int* __restrict__ cnt) {
    int e = blockIdx.x * blockDim.x + threadIdx.x;
    if (e < E) atomicAdd(&cnt[rows[e]], 1);
}

__global__ __launch_bounds__(1024) void scan1_kernel(const int* __restrict__ cnt, int N,
                                                     int* __restrict__ start,
                                                     int* __restrict__ partials) {
    __shared__ int s[1024];
    int tid = threadIdx.x;
    int i = blockIdx.x * 1024 + tid;
    int v = (i < N) ? cnt[i] : 0;
    s[tid] = v;
    __syncthreads();
    for (int off = 1; off < 1024; off <<= 1) {
        int t = (tid >= off) ? s[tid - off] : 0;
        __syncthreads();
        s[tid] += t;
        __syncthreads();
    }
    if (i < N) start[i] = s[tid] - v;   // exclusive scan within block
    if (tid == 1023) partials[blockIdx.x] = s[tid];
}

__global__ void scan2_kernel(int* __restrict__ partials, int nb) {
    int lane = threadIdx.x;  // single wave of 64; nb <= 64
    int v = (lane < nb) ? partials[lane] : 0;
    int incl = v;
    #pragma unroll
    for (int off = 1; off < 64; off <<= 1) {
        int t = __shfl_up(incl, off, 64);
        if (lane >= off) incl += t;
    }
    if (lane < nb) partials[lane] = incl - v;  // exclusive block offsets
}

__global__ __launch_bounds__(1024) void scan3_kernel(int* __restrict__ start,
                                                     const int* __restrict__ partials, int N,
                                                     int* __restrict__ cursor) {
    int i = blockIdx.x * 1024 + threadIdx.x;
    if (i < N) {
        int v = start[i] + partials[blockIdx.x];
        start[i] = v;
        cursor[i] = v;
    }
}

__global__ void scatter_kernel(const int* __restrict__ rows, const int* __restrict__ cols,
                               const float* __restrict__ vals, int E,
                               int* __restrict__ cursor,
                               int* __restrict__ ccols, float* __restrict__ cvals) {
    int e = blockIdx.x * blockDim.x + threadIdx.x;
    if (e < E) {
        int r = rows[e];
        int p = atomicAdd(&cursor[r], 1);
        ccols[p] = cols[e];
        cvals[p] = vals[e];
    }
}

// ---------------- GEMM1: support1 = x @ w1  (fp32, memory-bound on x) ----------------

#define XS_LD 132  // 128 + 4 pad: breaks 8-way bank aliasing on per-row b128 reads

__global__ __launch_bounds__(256) void gemm1_kernel(const float* __restrict__ x,
                                                    const float* __restrict__ w,
                                                    float* __restrict__ out, int N) {
    __shared__ float xs[32 * XS_LD];  // 32 rows x 128 k
    __shared__ float ws[128 * HID];   // 128 k x 32 d
    int tid = threadIdx.x;
    int r  = tid >> 3;   // 0..31 local row
    int d0 = (tid & 7) * 4;
    int row0 = blockIdx.x * 32;

    float4 acc = make_float4(0.f, 0.f, 0.f, 0.f);

    for (int kc = 0; kc < IN_DIM; kc += 128) {
        // stage x tile: 32 rows x 128 cols, float4-coalesced
        #pragma unroll
        for (int j = 0; j < 4; ++j) {
            int linear = tid + j * 256;
            int rr = linear >> 5;
            int cc = linear & 31;
            int grow = row0 + rr;
            if (grow > N - 1) grow = N - 1;  // clamp (dup read, store guarded later)
            float4 t = *(const float4*)&x[(size_t)grow * IN_DIM + kc + cc * 4];
            *(float4*)&xs[rr * XS_LD + cc * 4] = t;
        }
        // stage w tile: 128 k x 32 d
        #pragma unroll
        for (int j = 0; j < 4; ++j) {
            int linear = tid + j * 256;
            int kk = linear >> 3;
            int dd = (linear & 7) * 4;
            float4 t = *(const float4*)&w[(kc + kk) * HID + dd];
            *(float4*)&ws[kk * HID + dd] = t;
        }
        __syncthreads();
        #pragma unroll
        for (int k4 = 0; k4 < 32; ++k4) {
            float4 xv = *(const float4*)&xs[r * XS_LD + k4 * 4];
            float4 wv0 = *(const float4*)&ws[(k4 * 4 + 0) * HID + d0];
            acc.x += xv.x * wv0.x; acc.y += xv.x * wv0.y; acc.z += xv.x * wv0.z; acc.w += xv.x * wv0.w;
            float4 wv1 = *(const float4*)&ws[(k4 * 4 + 1) * HID + d0];
            acc.x += xv.y * wv1.x; acc.y += xv.y * wv1.y; acc.z += xv.y * wv1.z; acc.w += xv.y * wv1.w;
            float4 wv2 = *(const float4*)&ws[(k4 * 4 + 2) * HID + d0];
            acc.x += xv.z * wv2.x; acc.y += xv.z * wv2.y; acc.z += xv.z * wv2.z; acc.w += xv.z * wv2.w;
            float4 wv3 = *(const float4*)&ws[(k4 * 4 + 3) * HID + d0];
            acc.x += xv.w * wv3.x; acc.y += xv.w * wv3.y; acc.z += xv.w * wv3.z; acc.w += xv.w * wv3.w;
        }
        __syncthreads();
    }
    int grow = row0 + r;
    if (grow < N) *(float4*)&out[(size_t)grow * HID + d0] = acc;
}

// ---------------- SpMM + selu + bias (+ fused next-layer 32x32 GEMM) ----------------

__global__ __launch_bounds__(256) void spmm_mid_kernel(const float* __restrict__ sup,
                                                       const int* __restrict__ start,
                                                       const int* __restrict__ cnt,
                                                       const int* __restrict__ ccols,
                                                       const float* __restrict__ cvals,
                                                       const float* __restrict__ bias,
                                                       const float* __restrict__ Wn,
                                                       float* __restrict__ out, int N) {
    __shared__ float Wsh[HID * HID];
    __shared__ float hs[8][HID + 1];
    int tid = threadIdx.x;
    {   // stage W_next (32x32)
        float4 t = *(const float4*)&Wn[tid * 4];
        *(float4*)&Wsh[tid * 4] = t;
    }
    int rg = tid >> 5, d = tid & 31;
    int row = blockIdx.x * 8 + rg;
    float acc = 0.f;
    if (row < N) {
        int s0 = start[row];
        int e2 = s0 + cnt[row];
        int i = s0;
        for (; i + 4 <= e2; i += 4) {  // 4 gathers in flight
            int   c0 = ccols[i], c1 = ccols[i + 1], c2 = ccols[i + 2], c3 = ccols[i + 3];
            float v0 = cvals[i], v1 = cvals[i + 1], v2 = cvals[i + 2], v3 = cvals[i + 3];
            float g0 = sup[c0 * HID + d], g1 = sup[c1 * HID + d];
            float g2 = sup[c2 * HID + d], g3 = sup[c3 * HID + d];
            acc += v0 * g0 + v1 * g1 + v2 * g2 + v3 * g3;
        }
        for (; i < e2; ++i) acc += cvals[i] * sup[ccols[i] * HID + d];
    }
    float h = selu_f(acc) + bias[d];
    hs[rg][d] = h;
    __syncthreads();
    float o = 0.f;
    #pragma unroll
    for (int j = 0; j < HID; ++j) o += hs[rg][j] * Wsh[j * HID + d];
    if (row < N) out[(size_t)row * HID + d] = o;
}

__global__ __launch_bounds__(256) void spmm_final_kernel(const float* __restrict__ sup,
                                                         const int* __restrict__ start,
                                                         const int* __restrict__ cnt,
                                                         const int* __restrict__ ccols,
                                                         const float* __restrict__ cvals,
                                                         const float* __restrict__ bias,
                                                         const float* __restrict__ cw0,
                                                         const float* __restrict__ cb0,
                                                         const float* __restrict__ cw1,
                                                         const float* __restrict__ cb1,
                                                         float* __restrict__ out, int N) {
    __shared__ float hs[8][HID + 1];
    int tid = threadIdx.x;
    int rg = tid >> 5, d = tid & 31;
    int row = blockIdx.x * 8 + rg;
    float acc = 0.f;
    if (row < N) {
        int s0 = start[row];
        int e2 = s0 + cnt[row];
        int i = s0;
        for (; i + 4 <= e2; i += 4) {
            int   c0 = ccols[i], c1 = ccols[i + 1], c2 = ccols[i + 2], c3 = ccols[i + 3];
            float v0 = cvals[i], v1 = cvals[i + 1], v2 = cvals[i + 2], v3 = cvals[i + 3];
            float g0 = sup[c0 * HID + d], g1 = sup[c1 * HID + d];
            float g2 = sup[c2 * HID + d], g3 = sup[c3 * HID + d];
            acc += v0 * g0 + v1 * g1 + v2 * g2 + v3 * g3;
        }
        for (; i < e2; ++i) acc += cvals[i] * sup[ccols[i] * HID + d];
    }
    float h = selu_f(acc) + bias[d];
    hs[rg][d] = h;
    __syncthreads();
    if (row < N) {
        if (d < 2) {            // head 0: out0[row][d] = h . cw0[d,:] + cb0[d]
            float o = cb0[d];
            #pragma unroll
            for (int j = 0; j < HID; ++j) o += hs[rg][j] * cw0[d * HID + j];
            out[(size_t)row * 2 + d] = o;
        } else if (d < 5) {     // head 1: out1[row][c] = h . cw1[c,:] + cb1[c]
            int c = d - 2;
            float o = cb1[c];
            #pragma unroll
            for (int j = 0; j < HID; ++j) o += hs[rg][j] * cw1[c * HID + j];
            out[(size_t)N * 2 + (size_t)row * 3 + c] = o;
        }
    }
}

// ---------------- launch ----------------

extern "C" void kernel_launch(void* const* d_in, const int* in_sizes, int n_in,
                              void* d_out, int out_size, void* d_ws, size_t ws_size,
                              hipStream_t stream) {
    const float* x        = (const float*)d_in[0];
    const int*   adj_rows = (const int*)d_in[1];
    const int*   adj_cols = (const int*)d_in[2];
    const float* adj_vals = (const float*)d_in[3];
    const float* w1 = (const float*)d_in[4];
    const float* b1 = (const float*)d_in[5];
    const float* w2 = (const float*)d_in[6];
    const float* b2 = (const float*)d_in[7];
    const float* w3 = (const float*)d_in[8];
    const float* b3 = (const float*)d_in[9];
    const float* cw0 = (const float*)d_in[10];
    const float* cb0 = (const float*)d_in[11];
    const float* cw1 = (const float*)d_in[12];
    const float* cb1 = (const float*)d_in[13];

    int N = in_sizes[0] / IN_DIM;   // 50000
    int E = in_sizes[1];            // 1.6M

    char* p = (char*)d_ws;
    float* s_a   = (float*)p; p += (size_t)N * HID * sizeof(float);
    float* s_b   = (float*)p; p += (size_t)N * HID * sizeof(float);
    int*   ccols = (int*)p;   p += (size_t)E * sizeof(int);
    float* cvals = (float*)p; p += (size_t)E * sizeof(float);
    int*   rstart   = (int*)p; p += (size_t)N * sizeof(int);
    int*   rcnt     = (int*)p; p += (size_t)N * sizeof(int);
    int*   cursor   = (int*)p; p += (size_t)N * sizeof(int);
    int*   partials = (int*)p; p += 64 * sizeof(int);

    int nb = (N + 1023) / 1024;  // 49 (<= 64, fits scan2's single wave)

    // CSR build (once per call; reused by all 3 SpMM layers)
    zero_i32<<<(N + 255) / 256, 256, 0, stream>>>(rcnt, N);
    hist_kernel<<<(E + 255) / 256, 256, 0, stream>>>(adj_rows, E, rcnt);
    scan1_kernel<<<nb, 1024, 0, stream>>>(rcnt, N, rstart, partials);
    scan2_kernel<<<1, 64, 0, stream>>>(partials, nb);
    scan3_kernel<<<nb, 1024, 0, stream>>>(rstart, partials, N, cursor);
    scatter_kernel<<<(E + 255) / 256, 256, 0, stream>>>(adj_rows, adj_cols, adj_vals, E,
                                                        cursor, ccols, cvals);

    // Layer pipeline
    gemm1_kernel<<<(N + 31) / 32, 256, 0, stream>>>(x, w1, s_a, N);
    spmm_mid_kernel<<<(N + 7) / 8, 256, 0, stream>>>(s_a, rstart, rcnt, ccols, cvals,
                                                     b1, w2, s_b, N);
    spmm_mid_kernel<<<(N + 7) / 8, 256, 0, stream>>>(s_b, rstart, rcnt, ccols, cvals,
                                                     b2, w3, s_a, N);
    spmm_final_kernel<<<(N + 7) / 8, 256, 0, stream>>>(s_a, rstart, rcnt, ccols, cvals,
                                                       b3, cw0, cb0, cw1, cb1,
                                                       (float*)d_out, N);
}

// Round 2
// 624.145 us; speedup vs baseline: 1.0417x; 1.0417x over previous
//
#include <hip/hip_runtime.h>

#define IN_DIM 1024
#define HID 32

__device__ __forceinline__ float selu_f(float x) {
    const float scale = 1.0507009873554805f;
    const float alpha = 1.6732632423543772f;
    return x > 0.f ? scale * x : scale * alpha * (expf(x) - 1.f);
}

// ---------------- CSR build ----------------

__global__ void hist_kernel(const int* __restrict__ rows, int E, int* __restrict__ cnt) {
    int e = blockIdx.x * blockDim.x + threadIdx.x;
    if (e < E) atomicAdd(&cnt[rows[e]], 1);
}

__global__ __launch_bounds__(1024) void scan1_kernel(const int* __restrict__ cnt, int N,
                                                     int* __restrict__ start,
                                                     int* __restrict__ partials) {
    __shared__ int s[1024];
    int tid = threadIdx.x;
    int i = blockIdx.x * 1024 + tid;
    int v = (i < N) ? cnt[i] : 0;
    s[tid] = v;
    __syncthreads();
    for (int off = 1; off < 1024; off <<= 1) {
        int t = (tid >= off) ? s[tid - off] : 0;
        __syncthreads();
        s[tid] += t;
        __syncthreads();
    }
    if (i < N) start[i] = s[tid] - v;   // exclusive scan within block
    if (tid == 1023) partials[blockIdx.x] = s[tid];
}

__global__ void scan2_kernel(int* __restrict__ partials, int nb) {
    int lane = threadIdx.x;  // single wave of 64; nb <= 64
    int v = (lane < nb) ? partials[lane] : 0;
    int incl = v;
    #pragma unroll
    for (int off = 1; off < 64; off <<= 1) {
        int t = __shfl_up(incl, off, 64);
        if (lane >= off) incl += t;
    }
    if (lane < nb) partials[lane] = incl - v;  // exclusive block offsets
}

__global__ __launch_bounds__(1024) void scan3_kernel(int* __restrict__ start,
                                                     const int* __restrict__ partials, int N,
                                                     int* __restrict__ cursor) {
    int i = blockIdx.x * 1024 + threadIdx.x;
    if (i < N) {
        int v = start[i] + partials[blockIdx.x];
        start[i] = v;
        cursor[i] = v;
    }
}

// Packed scatter: ONE random 8B store per edge (col,val packed) instead of two 4B
__global__ void scatter_kernel(const int* __restrict__ rows, const int* __restrict__ cols,
                               const float* __restrict__ vals, int E,
                               int* __restrict__ cursor,
                               int2* __restrict__ edata) {
    int e = blockIdx.x * blockDim.x + threadIdx.x;
    if (e < E) {
        int r = rows[e];
        int2 pr;
        pr.x = cols[e];
        pr.y = __float_as_int(vals[e]);
        int p = atomicAdd(&cursor[r], 1);
        edata[p] = pr;
    }
}

// ---------------- GEMM1: support1 = x @ w1  (fp32, memory-bound on x) ----------------

#define XS_LD 132  // 128 + 4 pad: breaks 8-way bank aliasing on per-row b128 reads

__global__ __launch_bounds__(256) void gemm1_kernel(const float* __restrict__ x,
                                                    const float* __restrict__ w,
                                                    float* __restrict__ out, int N) {
    __shared__ float xs[32 * XS_LD];  // 32 rows x 128 k
    __shared__ float ws[128 * HID];   // 128 k x 32 d
    int tid = threadIdx.x;
    int r  = tid >> 3;   // 0..31 local row
    int d0 = (tid & 7) * 4;
    int row0 = blockIdx.x * 32;

    float4 acc = make_float4(0.f, 0.f, 0.f, 0.f);

    for (int kc = 0; kc < IN_DIM; kc += 128) {
        #pragma unroll
        for (int j = 0; j < 4; ++j) {
            int linear = tid + j * 256;
            int rr = linear >> 5;
            int cc = linear & 31;
            int grow = row0 + rr;
            if (grow > N - 1) grow = N - 1;  // clamp (dup read, store guarded later)
            float4 t = *(const float4*)&x[(size_t)grow * IN_DIM + kc + cc * 4];
            *(float4*)&xs[rr * XS_LD + cc * 4] = t;
        }
        #pragma unroll
        for (int j = 0; j < 4; ++j) {
            int linear = tid + j * 256;
            int kk = linear >> 3;
            int dd = (linear & 7) * 4;
            float4 t = *(const float4*)&w[(kc + kk) * HID + dd];
            *(float4*)&ws[kk * HID + dd] = t;
        }
        __syncthreads();
        #pragma unroll
        for (int k4 = 0; k4 < 32; ++k4) {
            float4 xv = *(const float4*)&xs[r * XS_LD + k4 * 4];
            float4 wv0 = *(const float4*)&ws[(k4 * 4 + 0) * HID + d0];
            acc.x += xv.x * wv0.x; acc.y += xv.x * wv0.y; acc.z += xv.x * wv0.z; acc.w += xv.x * wv0.w;
            float4 wv1 = *(const float4*)&ws[(k4 * 4 + 1) * HID + d0];
            acc.x += xv.y * wv1.x; acc.y += xv.y * wv1.y; acc.z += xv.y * wv1.z; acc.w += xv.y * wv1.w;
            float4 wv2 = *(const float4*)&ws[(k4 * 4 + 2) * HID + d0];
            acc.x += xv.z * wv2.x; acc.y += xv.z * wv2.y; acc.z += xv.z * wv2.z; acc.w += xv.z * wv2.w;
            float4 wv3 = *(const float4*)&ws[(k4 * 4 + 3) * HID + d0];
            acc.x += xv.w * wv3.x; acc.y += xv.w * wv3.y; acc.z += xv.w * wv3.z; acc.w += xv.w * wv3.w;
        }
        __syncthreads();
    }
    int grow = row0 + r;
    if (grow < N) *(float4*)&out[(size_t)grow * HID + d0] = acc;
}

// ---------------- SpMM + selu + bias (+ fused next-layer 32x32 GEMM) ----------------
// One 32-lane group per row. Edge meta loaded cooperatively (lane d reads edge s0+base+d,
// one coalesced 256B read per 32 edges) and broadcast via __shfl within the 32-lane group.

__device__ __forceinline__ float spmm_row_acc(const float* __restrict__ sup,
                                              const int2* __restrict__ edata,
                                              int s0, int c, int d) {
    float acc = 0.f;
    for (int base = 0; base < c; base += 32) {
        int rem = c - base;
        int m = rem < 32 ? rem : 32;
        int lidx = d < m ? d : m - 1;          // clamp: duplicate read, unused lanes
        int2 e = edata[s0 + base + lidx];
        int j = 0;
        for (; j + 4 <= m; j += 4) {
            int   c0 = __shfl(e.x, j, 32),     c1 = __shfl(e.x, j + 1, 32);
            int   c2 = __shfl(e.x, j + 2, 32), c3 = __shfl(e.x, j + 3, 32);
            float v0 = __int_as_float(__shfl(e.y, j, 32));
            float v1 = __int_as_float(__shfl(e.y, j + 1, 32));
            float v2 = __int_as_float(__shfl(e.y, j + 2, 32));
            float v3 = __int_as_float(__shfl(e.y, j + 3, 32));
            float g0 = sup[c0 * HID + d], g1 = sup[c1 * HID + d];
            float g2 = sup[c2 * HID + d], g3 = sup[c3 * HID + d];
            acc += v0 * g0 + v1 * g1 + v2 * g2 + v3 * g3;
        }
        for (; j < m; ++j) {
            int   cc = __shfl(e.x, j, 32);
            float vv = __int_as_float(__shfl(e.y, j, 32));
            acc += vv * sup[cc * HID + d];
        }
    }
    return acc;
}

__global__ __launch_bounds__(256) void spmm_mid_kernel(const float* __restrict__ sup,
                                                       const int* __restrict__ start,
                                                       const int* __restrict__ cnt,
                                                       const int2* __restrict__ edata,
                                                       const float* __restrict__ bias,
                                                       const float* __restrict__ Wn,
                                                       float* __restrict__ out, int N) {
    __shared__ float Wsh[HID * HID];
    __shared__ float hs[8][HID + 1];
    int tid = threadIdx.x;
    {   // stage W_next (32x32)
        float4 t = *(const float4*)&Wn[tid * 4];
        *(float4*)&Wsh[tid * 4] = t;
    }
    int rg = tid >> 5, d = tid & 31;
    int row = blockIdx.x * 8 + rg;
    float acc = 0.f;
    if (row < N) acc = spmm_row_acc(sup, edata, start[row], cnt[row], d);
    float h = selu_f(acc) + bias[d];
    hs[rg][d] = h;
    __syncthreads();
    float o = 0.f;
    #pragma unroll
    for (int j = 0; j < HID; ++j) o += hs[rg][j] * Wsh[j * HID + d];
    if (row < N) out[(size_t)row * HID + d] = o;
}

__global__ __launch_bounds__(256) void spmm_final_kernel(const float* __restrict__ sup,
                                                         const int* __restrict__ start,
                                                         const int* __restrict__ cnt,
                                                         const int2* __restrict__ edata,
                                                         const float* __restrict__ bias,
                                                         const float* __restrict__ cw0,
                                                         const float* __restrict__ cb0,
                                                         const float* __restrict__ cw1,
                                                         const float* __restrict__ cb1,
                                                         float* __restrict__ out, int N) {
    __shared__ float hs[8][HID + 1];
    int tid = threadIdx.x;
    int rg = tid >> 5, d = tid & 31;
    int row = blockIdx.x * 8 + rg;
    float acc = 0.f;
    if (row < N) acc = spmm_row_acc(sup, edata, start[row], cnt[row], d);
    float h = selu_f(acc) + bias[d];
    hs[rg][d] = h;
    __syncthreads();
    if (row < N) {
        if (d < 2) {            // head 0
            float o = cb0[d];
            #pragma unroll
            for (int j = 0; j < HID; ++j) o += hs[rg][j] * cw0[d * HID + j];
            out[(size_t)row * 2 + d] = o;
        } else if (d < 5) {     // head 1
            int c = d - 2;
            float o = cb1[c];
            #pragma unroll
            for (int j = 0; j < HID; ++j) o += hs[rg][j] * cw1[c * HID + j];
            out[(size_t)N * 2 + (size_t)row * 3 + c] = o;
        }
    }
}

// ---------------- launch ----------------

extern "C" void kernel_launch(void* const* d_in, const int* in_sizes, int n_in,
                              void* d_out, int out_size, void* d_ws, size_t ws_size,
                              hipStream_t stream) {
    const float* x        = (const float*)d_in[0];
    const int*   adj_rows = (const int*)d_in[1];
    const int*   adj_cols = (const int*)d_in[2];
    const float* adj_vals = (const float*)d_in[3];
    const float* w1 = (const float*)d_in[4];
    const float* b1 = (const float*)d_in[5];
    const float* w2 = (const float*)d_in[6];
    const float* b2 = (const float*)d_in[7];
    const float* w3 = (const float*)d_in[8];
    const float* b3 = (const float*)d_in[9];
    const float* cw0 = (const float*)d_in[10];
    const float* cb0 = (const float*)d_in[11];
    const float* cw1 = (const float*)d_in[12];
    const float* cb1 = (const float*)d_in[13];

    int N = in_sizes[0] / IN_DIM;   // 50000
    int E = in_sizes[1];            // 1.6M

    char* p = (char*)d_ws;
    float* s_a   = (float*)p; p += (size_t)N * HID * sizeof(float);
    float* s_b   = (float*)p; p += (size_t)N * HID * sizeof(float);
    int2*  edata = (int2*)p;  p += (size_t)E * sizeof(int2);
    int*   rstart   = (int*)p; p += (size_t)N * sizeof(int);
    int*   rcnt     = (int*)p; p += (size_t)N * sizeof(int);
    int*   cursor   = (int*)p; p += (size_t)N * sizeof(int);
    int*   partials = (int*)p; p += 64 * sizeof(int);

    int nb = (N + 1023) / 1024;  // 49 (<= 64, fits scan2's single wave)

    // CSR build (once per call; reused by all 3 SpMM layers)
    hipMemsetAsync(rcnt, 0, (size_t)N * sizeof(int), stream);
    hist_kernel<<<(E + 255) / 256, 256, 0, stream>>>(adj_rows, E, rcnt);
    scan1_kernel<<<nb, 1024, 0, stream>>>(rcnt, N, rstart, partials);
    scan2_kernel<<<1, 64, 0, stream>>>(partials, nb);
    scan3_kernel<<<nb, 1024, 0, stream>>>(rstart, partials, N, cursor);
    scatter_kernel<<<(E + 255) / 256, 256, 0, stream>>>(adj_rows, adj_cols, adj_vals, E,
                                                        cursor, edata);

    // Layer pipeline
    gemm1_kernel<<<(N + 31) / 32, 256, 0, stream>>>(x, w1, s_a, N);
    spmm_mid_kernel<<<(N + 7) / 8, 256, 0, stream>>>(s_a, rstart, rcnt, edata,
                                                     b1, w2, s_b, N);
    spmm_mid_kernel<<<(N + 7) / 8, 256, 0, stream>>>(s_b, rstart, rcnt, edata,
                                                     b2, w3, s_a, N);
    spmm_final_kernel<<<(N + 7) / 8, 256, 0, stream>>>(s_a, rstart, rcnt, edata,
                                                       b3, cw0, cb0, cw1, cb1,
                                                       (float*)d_out, N);
}